// Round 1
// baseline (189.240 us; speedup 1.0000x reference)
//
#include <hip/hip_runtime.h>

// DifferentiableTopK via Sinkhorn, restructured:
//   log_P = L0 - u_i - v_j  =>  only potentials evolve.
//   Sorted (value) domain: kernel M is symmetric, both half-iterations are the
//   same map x <- 1/(M x) (linear domain). 100 iters == 200 applications.
//   M is banded (exp(-(dv)^2/1e-3) ~ 0 beyond |dv|~0.3 => +-32 sorted indices).
//   Band kernel values live in 64 VGPRs per thread (one thread per sorted pos).

#define N      512
#define BATCH  16
#define KTOP   50
#define BW     64          // band width (indices), +-32 around diagonal
#define HALF   32
#define NAPPS  200         // 100 iterations x (col + row normalize)
#define COEF   1442.6950408889634f   // log2(e) / EPSILON, EPSILON = 1e-3

__global__ __launch_bounds__(512)
void sinkhorn_topk_kernel(const float* __restrict__ scores,
                          float* __restrict__ out) {
    __shared__ __align__(16) float tv[N];   // sorted values, descending
    __shared__ int                 ti[N];   // original index of each rank
    __shared__ __align__(16) float xA[N];   // scaling vector, double buffered
    __shared__ __align__(16) float xB[N];

    const int tid = threadIdx.x;
    const int b   = blockIdx.x;

    tv[tid] = scores[b * N + tid];
    ti[tid] = tid;
    __syncthreads();

    // ---- bitonic sort, descending (value,index) ----
    for (int k = 2; k <= N; k <<= 1) {
        for (int j = k >> 1; j > 0; j >>= 1) {
            int ixj = tid ^ j;
            if (ixj > tid) {
                float va = tv[tid], vb = tv[ixj];
                int   ia = ti[tid], ib = ti[ixj];
                bool up = ((tid & k) == 0);          // descending in "up" blocks
                bool sw = up ? (va < vb) : (va > vb);
                if (sw) { tv[tid] = vb; tv[ixj] = va; ti[tid] = ib; ti[ixj] = ia; }
            }
            __syncthreads();
        }
    }

    // ---- per-thread banded kernel row in registers ----
    // base aligned to 4 floats so x-band reads are float4 aligned.
    int base = tid - HALF;
    base = base < 0 ? 0 : base;
    base = base > (N - BW) ? (N - BW) : base;
    base &= ~3;

    const float tj = tv[tid];
    float Kreg[BW];
#pragma unroll
    for (int k = 0; k < BW; ++k) {
        float d = tj - tv[base + k];
        Kreg[k] = exp2f(-COEF * d * d);   // exp(-d^2/eps), v_exp_f32
    }

    xA[tid] = 1.0f;
    __syncthreads();

    // ---- 200 applications of x <- 1/(M x), double-buffered in LDS ----
    float* xr = xA;
    float* xw = xB;
    for (int t = 0; t < NAPPS; ++t) {
        const float4* xv = (const float4*)(xr + base);
        float a0 = 0.f, a1 = 0.f, a2 = 0.f, a3 = 0.f;
#pragma unroll
        for (int m = 0; m < BW / 4; ++m) {
            float4 v = xv[m];
            a0 += Kreg[4 * m + 0] * v.x;
            a1 += Kreg[4 * m + 1] * v.y;
            a2 += Kreg[4 * m + 2] * v.z;
            a3 += Kreg[4 * m + 3] * v.w;
        }
        float y = (a0 + a1) + (a2 + a3);
        xw[tid] = 1.0f / y;
        __syncthreads();          // one barrier per application
        float* tmp = xr; xr = xw; xw = tmp;
    }
    // xr = r (last written, app 200), xw = c (app 199)

    // ---- epilogue: out_row = r_a * sum_{j<K} M_{a,j} c_j, scatter by rank ----
    float acc = 0.f;
#pragma unroll
    for (int k = 0; k < BW; ++k) {
        int idx = base + k;
        if (idx < KTOP) acc += Kreg[k] * xw[idx];
    }
    float w = xr[tid] * acc;
    out[b * N + ti[tid]] = w;
}

extern "C" void kernel_launch(void* const* d_in, const int* in_sizes, int n_in,
                              void* d_out, int out_size, void* d_ws, size_t ws_size,
                              hipStream_t stream) {
    const float* scores = (const float*)d_in[0];
    float* out = (float*)d_out;
    sinkhorn_topk_kernel<<<dim3(BATCH), dim3(N), 0, stream>>>(scores, out);
}

// Round 2
// 176.599 us; speedup vs baseline: 1.0716x; 1.0716x over previous
//
#include <hip/hip_runtime.h>

// Sinkhorn top-k, sorted-value domain, linear scaling iteration x <- 1/(Mx).
// R2: 2 adjacent rows per thread share one 52-float register x-window
// (halves LDS read traffic, the measured bottleneck); both rows' banded
// kernel values (2x52) live in registers.

#define N      512
#define BATCH  16
#define KTOP   50
#define WW     52          // shared window width (covers >= +-23 band; edge ~3e-6)
#define NW     (WW / 4)
#define NAPPS  200         // 100 iterations x (col + row normalize) - exact iterate
#define COEF   1442.6950408889634f   // log2(e) / EPSILON, EPSILON = 1e-3

__global__ __launch_bounds__(256, 1)
void sinkhorn_topk_kernel(const float* __restrict__ scores,
                          float* __restrict__ out) {
    __shared__ __align__(16) float tv[N];   // sorted values, descending
    __shared__ int                 ti[N];   // original index of each rank
    __shared__ __align__(16) float xA[N];   // scaling vector, double buffered
    __shared__ __align__(16) float xB[N];

    const int tid = threadIdx.x;
    const int b   = blockIdx.x;

    tv[tid]       = scores[b * N + tid];
    tv[tid + 256] = scores[b * N + tid + 256];
    ti[tid] = tid;
    ti[tid + 256] = tid + 256;
    __syncthreads();

    // ---- bitonic sort, descending; 256 threads, one compare-exchange each ----
    for (int k = 2; k <= N; k <<= 1) {
        for (int j = k >> 1; j > 0; j >>= 1) {
            int i = ((tid & ~(j - 1)) << 1) | (tid & (j - 1));
            int p = i | j;
            float va = tv[i], vb = tv[p];
            bool up = ((i & k) == 0);
            bool sw = up ? (va < vb) : (va > vb);
            if (sw) {
                tv[i] = vb; tv[p] = va;
                int t_ = ti[i]; ti[i] = ti[p]; ti[p] = t_;
            }
            __syncthreads();
        }
    }

    // ---- two rows per thread; shared aligned window ----
    const int r0 = 2 * tid, r1 = 2 * tid + 1;
    int wb = r0 - 24;
    wb = wb < 0 ? 0 : wb;
    wb = wb > (N - WW) ? (N - WW) : wb;
    wb &= ~3;                                // float4-aligned window base

    const float t0 = tv[r0], t1 = tv[r1];
    float K0[WW], K1[WW];
#pragma unroll
    for (int m = 0; m < WW; ++m) {
        float s  = tv[wb + m];
        float d0 = t0 - s, d1 = t1 - s;
        K0[m] = exp2f(-COEF * d0 * d0);      // exp(-d^2/eps)
        K1[m] = exp2f(-COEF * d1 * d1);
    }

    xA[r0] = 1.0f; xA[r1] = 1.0f;
    __syncthreads();

    // ---- 200 applications of x <- 1/(M x) ----
    float* xr = xA;
    float* xw = xB;
    for (int t = 0; t < NAPPS; ++t) {
        const float4* wv = (const float4*)(xr + wb);
        float a0 = 0.f, a1 = 0.f, a2 = 0.f, a3 = 0.f;
        float c0 = 0.f, c1 = 0.f, c2 = 0.f, c3 = 0.f;
#pragma unroll
        for (int m = 0; m < NW; ++m) {
            float4 w = wv[m];
            a0 += K0[4 * m + 0] * w.x;
            a1 += K0[4 * m + 1] * w.y;
            a2 += K0[4 * m + 2] * w.z;
            a3 += K0[4 * m + 3] * w.w;
            c0 += K1[4 * m + 0] * w.x;
            c1 += K1[4 * m + 1] * w.y;
            c2 += K1[4 * m + 2] * w.z;
            c3 += K1[4 * m + 3] * w.w;
        }
        float y0 = (a0 + a1) + (a2 + a3);
        float y1 = (c0 + c1) + (c2 + c3);
        float2 o;
        o.x = 1.0f / y0;
        o.y = 1.0f / y1;
        ((float2*)xw)[tid] = o;              // rows 2t, 2t+1 contiguous
        __syncthreads();
        float* tmp = xr; xr = xw; xw = tmp;
    }
    // xr = r (app 200), xw = c (app 199)

    // ---- epilogue: out_row = r_a * sum_{j<K} M_{a,j} c_j, scatter by rank ----
    float acc0 = 0.f, acc1 = 0.f;
#pragma unroll
    for (int m = 0; m < WW; ++m) {
        int col = wb + m;
        if (col < KTOP) {
            float cc = xw[col];
            acc0 += K0[m] * cc;
            acc1 += K1[m] * cc;
        }
    }
    out[b * N + ti[r0]] = xr[r0] * acc0;
    out[b * N + ti[r1]] = xr[r1] * acc1;
}

extern "C" void kernel_launch(void* const* d_in, const int* in_sizes, int n_in,
                              void* d_out, int out_size, void* d_ws, size_t ws_size,
                              hipStream_t stream) {
    const float* scores = (const float*)d_in[0];
    float* out = (float*)d_out;
    sinkhorn_topk_kernel<<<dim3(BATCH), dim3(256), 0, stream>>>(scores, out);
}

// Round 3
// 148.890 us; speedup vs baseline: 1.2710x; 1.1861x over previous
//
#include <hip/hip_runtime.h>

// Sinkhorn top-k, sorted-value domain, linear scaling iteration x <- 1/(Mx).
// R3: 4 rows per lane => window reads are lane-stride 16 B, the canonical
// contiguous ds_read_b128 pattern (conflict-free), and VALU/LDS rebalance to
// ~400 cyc/app. K (4x44 floats) lives in registers; 128 thr/block, 1 batch/CU.

#define N      512
#define BATCH  16
#define KTOP   50
#define WW     44          // window floats per lane (min radius +-20)
#define NW     (WW / 4)    // 11 float4 reads
#define NAPPS  200         // 100 iterations x (col + row normalize) - exact iterate
#define COEF   1442.6950408889634f   // log2(e) / EPSILON, EPSILON = 1e-3

__global__ __launch_bounds__(128, 1)
void sinkhorn_topk_kernel(const float* __restrict__ scores,
                          float* __restrict__ out) {
    __shared__ __align__(16) float tv[N];   // sorted values, descending
    __shared__ int                 ti[N];   // original index of each rank
    __shared__ __align__(16) float xA[N];   // scaling vector, double buffered
    __shared__ __align__(16) float xB[N];

    const int tid = threadIdx.x;            // 0..127
    const int b   = blockIdx.x;

    // load 4 contiguous scores per thread
    ((float4*)tv)[tid] = ((const float4*)(scores + b * N))[tid];
    ((int4*)ti)[tid]   = make_int4(4 * tid, 4 * tid + 1, 4 * tid + 2, 4 * tid + 3);
    __syncthreads();

    // ---- bitonic sort, descending; 128 threads x 2 compare-exchanges/step ----
    for (int k = 2; k <= N; k <<= 1) {
        for (int j = k >> 1; j > 0; j >>= 1) {
#pragma unroll
            for (int e = 0; e < 2; ++e) {
                int q = tid + e * 128;                    // pair id, 0..255
                int i = ((q & ~(j - 1)) << 1) | (q & (j - 1));
                int p = i | j;
                float va = tv[i], vb = tv[p];
                bool up = ((i & k) == 0);
                bool sw = up ? (va < vb) : (va > vb);
                if (sw) {
                    tv[i] = vb; tv[p] = va;
                    int t_ = ti[i]; ti[i] = ti[p]; ti[p] = t_;
                }
            }
            __syncthreads();
        }
    }

    // ---- per-lane rows 4*tid .. 4*tid+3; shared aligned window ----
    const int r0 = 4 * tid;
    int wb = r0 - 20;                        // already 4-aligned
    wb = wb < 0 ? 0 : wb;
    wb = wb > (N - WW) ? (N - WW) : wb;

    float trow[4];
#pragma unroll
    for (int r = 0; r < 4; ++r) trow[r] = tv[r0 + r];

    float K[4][WW];
#pragma unroll
    for (int m = 0; m < WW; ++m) {
        float s = tv[wb + m];
#pragma unroll
        for (int r = 0; r < 4; ++r) {
            float d = trow[r] - s;
            K[r][m] = exp2f(-COEF * d * d);  // exp(-d^2/eps)
        }
    }

    ((float4*)xA)[tid] = make_float4(1.f, 1.f, 1.f, 1.f);
    __syncthreads();

    // ---- 200 applications of x <- 1/(M x) ----
    float* xr = xA;
    float* xw = xB;
    for (int t = 0; t < NAPPS; ++t) {
        const float4* wv = (const float4*)(xr + wb);
        float acc[4][4];
#pragma unroll
        for (int r = 0; r < 4; ++r)
#pragma unroll
            for (int c = 0; c < 4; ++c) acc[r][c] = 0.f;

#pragma unroll
        for (int m = 0; m < NW; ++m) {
            float4 w = wv[m];
#pragma unroll
            for (int r = 0; r < 4; ++r) {
                acc[r][0] += K[r][4 * m + 0] * w.x;
                acc[r][1] += K[r][4 * m + 1] * w.y;
                acc[r][2] += K[r][4 * m + 2] * w.z;
                acc[r][3] += K[r][4 * m + 3] * w.w;
            }
        }
        float4 o;
        o.x = 1.0f / ((acc[0][0] + acc[0][1]) + (acc[0][2] + acc[0][3]));
        o.y = 1.0f / ((acc[1][0] + acc[1][1]) + (acc[1][2] + acc[1][3]));
        o.z = 1.0f / ((acc[2][0] + acc[2][1]) + (acc[2][2] + acc[2][3]));
        o.w = 1.0f / ((acc[3][0] + acc[3][1]) + (acc[3][2] + acc[3][3]));
        ((float4*)xw)[tid] = o;              // rows 4t..4t+3 contiguous
        __syncthreads();
        float* tmp = xr; xr = xw; xw = tmp;
    }
    // xr = r (app 200), xw = c (app 199)

    // ---- epilogue: out_row = r_a * sum_{j<K} M_{a,j} c_j, scatter by rank ----
    float acc[4] = {0.f, 0.f, 0.f, 0.f};
#pragma unroll
    for (int m = 0; m < WW; ++m) {
        int col = wb + m;
        if (col < KTOP) {
            float cc = xw[col];
#pragma unroll
            for (int r = 0; r < 4; ++r) acc[r] += K[r][m] * cc;
        }
    }
#pragma unroll
    for (int r = 0; r < 4; ++r)
        out[b * N + ti[r0 + r]] = xr[r0 + r] * acc[r];
}

extern "C" void kernel_launch(void* const* d_in, const int* in_sizes, int n_in,
                              void* d_out, int out_size, void* d_ws, size_t ws_size,
                              hipStream_t stream) {
    const float* scores = (const float*)d_in[0];
    float* out = (float*)d_out;
    sinkhorn_topk_kernel<<<dim3(BATCH), dim3(128), 0, stream>>>(scores, out);
}